// Round 1
// baseline (6184.640 us; speedup 1.0000x reference)
//
#include <hip/hip_runtime.h>

#define D 128

// ---- degree count: one float atomic per edge ----
__global__ void count_kernel(const int* __restrict__ dst, int E, float* __restrict__ cnt) {
    int i = blockIdx.x * blockDim.x + threadIdx.x;
    if (i < E) atomicAdd(&cnt[dst[i]], 1.0f);
}

// ---- scatter-add: 32 threads per edge, float4 gather, 4 f32 atomics each ----
__global__ void scatter_kernel(const float4* __restrict__ x, const int* __restrict__ src,
                               const int* __restrict__ dst, int E, float* __restrict__ agg) {
    int gid = blockIdx.x * blockDim.x + threadIdx.x;
    int total = E * 32;
    if (gid >= total) return;
    int e = gid >> 5;
    int c = gid & 31;
    int s = src[e];
    int t = dst[e];
    float4 v = x[(long long)s * 32 + c];
    float* a = agg + (long long)t * D + c * 4;
    atomicAdd(a + 0, v.x);
    atomicAdd(a + 1, v.y);
    atomicAdd(a + 2, v.z);
    atomicAdd(a + 3, v.w);
}

// ---- finalize: agg = x + agg / max(cnt,1), in place, float4 ----
__global__ void finalize_kernel(const float4* __restrict__ x, float4* __restrict__ agg,
                                const float* __restrict__ cnt, int total4) {
    int i = blockIdx.x * blockDim.x + threadIdx.x;
    if (i >= total4) return;
    int row = i >> 5;                  // 32 float4 per row of 128
    float inv = 1.0f / fmaxf(cnt[row], 1.0f);
    float4 a = agg[i];
    float4 xv = x[i];
    a.x = xv.x + a.x * inv;
    a.y = xv.y + a.y * inv;
    a.z = xv.z + a.z * inv;
    a.w = xv.w + a.w * inv;
    agg[i] = a;
}

// ---- W [c][k] -> Wt [k][c] so GEMM weight loads are lane-coalesced ----
__global__ void transpose_kernel(const float* __restrict__ W, float* __restrict__ Wt) {
    int i = blockIdx.x * blockDim.x + threadIdx.x;
    if (i < D * D) {
        int c = i >> 7, k = i & 127;
        Wt[k * D + c] = W[i];
    }
}

// ---- out[row][col] = (relu?) in[row] . Wt[:,col] + b[col]; 8 rows/block ----
__global__ __launch_bounds__(256) void gemm_kernel(const float* __restrict__ in,
                                                   const float* __restrict__ Wt,
                                                   const float* __restrict__ b,
                                                   float* __restrict__ out,
                                                   int n_rows, int relu) {
    __shared__ float tile[8][D];
    int col = threadIdx.x & 127;
    int rh  = threadIdx.x >> 7;        // 0..1 -> rows 0-3 / 4-7
    int row0 = blockIdx.x * 8;
    {
        // 256 threads x float4 = 8 rows x 128 floats
        int r  = threadIdx.x >> 5;
        int cc = (threadIdx.x & 31) * 4;
        float4 v = make_float4(0.f, 0.f, 0.f, 0.f);
        if (row0 + r < n_rows)
            v = *(const float4*)(in + (long long)(row0 + r) * D + cc);
        tile[r][cc] = v.x; tile[r][cc + 1] = v.y; tile[r][cc + 2] = v.z; tile[r][cc + 3] = v.w;
    }
    __syncthreads();
    float acc[4] = {0.f, 0.f, 0.f, 0.f};
    int rbase = rh * 4;
    for (int k = 0; k < D; k += 4) {
        float w0 = Wt[(k + 0) * D + col];
        float w1 = Wt[(k + 1) * D + col];
        float w2 = Wt[(k + 2) * D + col];
        float w3 = Wt[(k + 3) * D + col];
#pragma unroll
        for (int r = 0; r < 4; ++r) {
            float4 xv = *(const float4*)&tile[rbase + r][k];   // LDS broadcast, conflict-free
            acc[r] += xv.x * w0 + xv.y * w1 + xv.z * w2 + xv.w * w3;
        }
    }
    float bb = b[col];
#pragma unroll
    for (int r = 0; r < 4; ++r) {
        int row = row0 + rbase + r;
        if (row < n_rows) {
            float v = acc[r] + bb;
            if (relu) v = fmaxf(v, 0.f);
            out[(long long)row * D + col] = v;
        }
    }
}

extern "C" void kernel_launch(void* const* d_in, const int* in_sizes, int n_in,
                              void* d_out, int out_size, void* d_ws, size_t ws_size,
                              hipStream_t stream) {
    const float* features = (const float*)d_in[0];
    const int*   src      = (const int*)d_in[1];
    const int*   dst      = (const int*)d_in[2];
    const float* W1       = (const float*)d_in[3];
    const float* b1       = (const float*)d_in[4];
    const float* W2       = (const float*)d_in[5];
    const float* b2       = (const float*)d_in[6];
    float* out = (float*)d_out;

    int N = in_sizes[0] / D;     // 100000
    int E = in_sizes[1];         // 1600000

    // ws layout: agg [N*D f32] | cnt [N f32] | Wt1 [D*D] | Wt2 [D*D]
    char* ws = (char*)d_ws;
    float* agg = (float*)ws;
    float* cnt = (float*)(ws + (size_t)N * D * 4);
    float* Wt1 = (float*)(ws + (size_t)N * D * 4 + (size_t)N * 4);
    float* Wt2 = Wt1 + D * D;

    // zero agg + cnt (contiguous)
    hipMemsetAsync(agg, 0, (size_t)N * D * 4 + (size_t)N * 4, stream);

    transpose_kernel<<<(D * D + 255) / 256, 256, 0, stream>>>(W1, Wt1);
    transpose_kernel<<<(D * D + 255) / 256, 256, 0, stream>>>(W2, Wt2);

    count_kernel<<<(E + 255) / 256, 256, 0, stream>>>(dst, E, cnt);

    // layer 1
    scatter_kernel<<<(E * 32 + 255) / 256, 256, 0, stream>>>(
        (const float4*)features, src, dst, E, agg);
    finalize_kernel<<<(N * 32 + 255) / 256, 256, 0, stream>>>(
        (const float4*)features, (float4*)agg, cnt, N * 32);
    gemm_kernel<<<(N + 7) / 8, 256, 0, stream>>>(agg, Wt1, b1, out, N, 1);  // x1 -> d_out

    // layer 2
    hipMemsetAsync(agg, 0, (size_t)N * D * 4, stream);
    scatter_kernel<<<(E * 32 + 255) / 256, 256, 0, stream>>>(
        (const float4*)out, src, dst, E, agg);
    finalize_kernel<<<(N * 32 + 255) / 256, 256, 0, stream>>>(
        (const float4*)out, (float4*)agg, cnt, N * 32);
    gemm_kernel<<<(N + 7) / 8, 256, 0, stream>>>(agg, Wt2, b2, out, N, 0);
}

// Round 2
// 1069.411 us; speedup vs baseline: 5.7832x; 5.7832x over previous
//
#include <hip/hip_runtime.h>

#define D 128

// =================== CSR build ===================

// degree histogram (int atomics)
__global__ void hist_kernel(const int* __restrict__ dst, int E, int* __restrict__ deg) {
    int i = blockIdx.x * blockDim.x + threadIdx.x;
    if (i < E) atomicAdd(&deg[dst[i]], 1);
}

// exclusive scan, stage A: 1024 items per block (256 thr x 4)
__global__ __launch_bounds__(256) void scanA_kernel(const int* __restrict__ deg,
                                                    int* __restrict__ row_ptr,
                                                    int* __restrict__ bsums, int N) {
    __shared__ int sd[256];
    int t = threadIdx.x;
    int base = blockIdx.x * 1024 + t * 4;
    int v[4]; int s = 0;
#pragma unroll
    for (int k = 0; k < 4; ++k) {
        v[k] = (base + k < N) ? deg[base + k] : 0;
        s += v[k];
    }
    sd[t] = s;
    __syncthreads();
    for (int off = 1; off < 256; off <<= 1) {
        int x = (t >= off) ? sd[t - off] : 0;
        __syncthreads();
        sd[t] += x;
        __syncthreads();
    }
    int excl = sd[t] - s;
    if (t == 255) bsums[blockIdx.x] = sd[255];
    int run = excl;
#pragma unroll
    for (int k = 0; k < 4; ++k) {
        if (base + k < N) row_ptr[base + k] = run;
        run += v[k];
    }
}

// stage B: single block scans block sums (chunked, supports any nb)
__global__ __launch_bounds__(256) void scanB_kernel(int* __restrict__ bsums, int nb) {
    __shared__ int sd[256];
    int t = threadIdx.x;
    int carry = 0;
    for (int base = 0; base < nb; base += 256) {
        int i = base + t;
        int v = (i < nb) ? bsums[i] : 0;
        sd[t] = v;
        __syncthreads();
        for (int off = 1; off < 256; off <<= 1) {
            int x = (t >= off) ? sd[t - off] : 0;
            __syncthreads();
            sd[t] += x;
            __syncthreads();
        }
        if (i < nb) bsums[i] = carry + sd[t] - v;
        int tot = sd[255];
        __syncthreads();
        carry += tot;
    }
}

// stage C: add block offsets; write row_ptr[N] = E
__global__ void scanC_kernel(int* __restrict__ row_ptr, const int* __restrict__ bsums,
                             int N, int E) {
    int i = blockIdx.x * blockDim.x + threadIdx.x;
    if (i < N) row_ptr[i] += bsums[i >> 10];
    if (i == 0) row_ptr[N] = E;
}

// bucket scatter: fill[] must be zeroed; one int atomic per edge
__global__ void bucket_kernel(const int* __restrict__ src, const int* __restrict__ dst, int E,
                              const int* __restrict__ row_ptr, int* __restrict__ fill,
                              int* __restrict__ src_sorted) {
    int e = blockIdx.x * blockDim.x + threadIdx.x;
    if (e < E) {
        int t = dst[e];
        int p = atomicAdd(&fill[t], 1);
        src_sorted[row_ptr[t] + p] = src[e];
    }
}

// =================== aggregation (pull, no atomics) ===================
// 32 threads per node, float4 per thread; out = x[node] + sum(x[src])/max(deg,1)
__global__ __launch_bounds__(256) void aggregate_kernel(const float4* __restrict__ x,
                                                        const int* __restrict__ row_ptr,
                                                        const int* __restrict__ src_sorted,
                                                        float4* __restrict__ out, int N) {
    int node = blockIdx.x * 8 + (threadIdx.x >> 5);
    if (node >= N) return;
    int c = threadIdx.x & 31;
    int beg = row_ptr[node], end = row_ptr[node + 1];
    float4 acc = make_float4(0.f, 0.f, 0.f, 0.f);
    int j = beg;
    for (; j + 4 <= end; j += 4) {
        int s0 = src_sorted[j + 0];
        int s1 = src_sorted[j + 1];
        int s2 = src_sorted[j + 2];
        int s3 = src_sorted[j + 3];
        float4 v0 = x[(size_t)s0 * 32 + c];
        float4 v1 = x[(size_t)s1 * 32 + c];
        float4 v2 = x[(size_t)s2 * 32 + c];
        float4 v3 = x[(size_t)s3 * 32 + c];
        acc.x += v0.x; acc.y += v0.y; acc.z += v0.z; acc.w += v0.w;
        acc.x += v1.x; acc.y += v1.y; acc.z += v1.z; acc.w += v1.w;
        acc.x += v2.x; acc.y += v2.y; acc.z += v2.z; acc.w += v2.w;
        acc.x += v3.x; acc.y += v3.y; acc.z += v3.z; acc.w += v3.w;
    }
    for (; j < end; ++j) {
        int s = src_sorted[j];
        float4 v = x[(size_t)s * 32 + c];
        acc.x += v.x; acc.y += v.y; acc.z += v.z; acc.w += v.w;
    }
    float inv = 1.0f / fmaxf((float)(end - beg), 1.0f);
    float4 xv = x[(size_t)node * 32 + c];
    float4 r;
    r.x = xv.x + acc.x * inv;
    r.y = xv.y + acc.y * inv;
    r.z = xv.z + acc.z * inv;
    r.w = xv.w + acc.w * inv;
    out[(size_t)node * 32 + c] = r;
}

// =================== fallback path (atomic scatter, proven R0) ===================

__global__ void count_kernel(const int* __restrict__ dst, int E, float* __restrict__ cnt) {
    int i = blockIdx.x * blockDim.x + threadIdx.x;
    if (i < E) atomicAdd(&cnt[dst[i]], 1.0f);
}

__global__ void scatter_kernel(const float4* __restrict__ x, const int* __restrict__ src,
                               const int* __restrict__ dst, int E, float* __restrict__ agg) {
    int gid = blockIdx.x * blockDim.x + threadIdx.x;
    int total = E * 32;
    if (gid >= total) return;
    int e = gid >> 5;
    int c = gid & 31;
    int s = src[e];
    int t = dst[e];
    float4 v = x[(size_t)s * 32 + c];
    float* a = agg + (size_t)t * D + c * 4;
    atomicAdd(a + 0, v.x);
    atomicAdd(a + 1, v.y);
    atomicAdd(a + 2, v.z);
    atomicAdd(a + 3, v.w);
}

__global__ void finalize_kernel(const float4* __restrict__ x, float4* __restrict__ agg,
                                const float* __restrict__ cnt, int total4) {
    int i = blockIdx.x * blockDim.x + threadIdx.x;
    if (i >= total4) return;
    int row = i >> 5;
    float inv = 1.0f / fmaxf(cnt[row], 1.0f);
    float4 a = agg[i];
    float4 xv = x[i];
    a.x = xv.x + a.x * inv;
    a.y = xv.y + a.y * inv;
    a.z = xv.z + a.z * inv;
    a.w = xv.w + a.w * inv;
    agg[i] = a;
}

// =================== weights + GEMM ===================

__global__ void transpose_kernel(const float* __restrict__ W, float* __restrict__ Wt) {
    int i = blockIdx.x * blockDim.x + threadIdx.x;
    if (i < D * D) {
        int c = i >> 7, k = i & 127;
        Wt[k * D + c] = W[i];
    }
}

// in-place-safe: block reads its 8 rows to LDS before writing them
__global__ __launch_bounds__(256) void gemm_kernel(const float* __restrict__ in,
                                                   const float* __restrict__ Wt,
                                                   const float* __restrict__ b,
                                                   float* __restrict__ out,
                                                   int n_rows, int relu) {
    __shared__ float tile[8][D];
    int col = threadIdx.x & 127;
    int rh  = threadIdx.x >> 7;
    int row0 = blockIdx.x * 8;
    {
        int r  = threadIdx.x >> 5;
        int cc = (threadIdx.x & 31) * 4;
        float4 v = make_float4(0.f, 0.f, 0.f, 0.f);
        if (row0 + r < n_rows)
            v = *(const float4*)(in + (size_t)(row0 + r) * D + cc);
        tile[r][cc] = v.x; tile[r][cc + 1] = v.y; tile[r][cc + 2] = v.z; tile[r][cc + 3] = v.w;
    }
    __syncthreads();
    float acc[4] = {0.f, 0.f, 0.f, 0.f};
    int rbase = rh * 4;
    for (int k = 0; k < D; k += 4) {
        float w0 = Wt[(k + 0) * D + col];
        float w1 = Wt[(k + 1) * D + col];
        float w2 = Wt[(k + 2) * D + col];
        float w3 = Wt[(k + 3) * D + col];
#pragma unroll
        for (int r = 0; r < 4; ++r) {
            float4 xv = *(const float4*)&tile[rbase + r][k];
            acc[r] += xv.x * w0 + xv.y * w1 + xv.z * w2 + xv.w * w3;
        }
    }
    float bb = b[col];
#pragma unroll
    for (int r = 0; r < 4; ++r) {
        int row = row0 + rbase + r;
        if (row < n_rows) {
            float v = acc[r] + bb;
            if (relu) v = fmaxf(v, 0.f);
            out[(size_t)row * D + col] = v;
        }
    }
}

extern "C" void kernel_launch(void* const* d_in, const int* in_sizes, int n_in,
                              void* d_out, int out_size, void* d_ws, size_t ws_size,
                              hipStream_t stream) {
    const float* features = (const float*)d_in[0];
    const int*   src      = (const int*)d_in[1];
    const int*   dst      = (const int*)d_in[2];
    const float* W1       = (const float*)d_in[3];
    const float* b1       = (const float*)d_in[4];
    const float* W2       = (const float*)d_in[5];
    const float* b2       = (const float*)d_in[6];
    float* out = (float*)d_out;

    int N = in_sizes[0] / D;     // 100000
    int E = in_sizes[1];         // 1600000
    int nb = (N + 1023) / 1024;  // scan blocks

    // ---- CSR-path ws layout ----
    // buf [N*D f32] | row_ptr [(N+1) i32] | deg/fill [N i32] | bsums [nb i32 pad]
    // | src_sorted [E i32] | Wt1 [D*D] | Wt2 [D*D]
    size_t off = 0;
    char* ws = (char*)d_ws;
    float* buf = (float*)(ws + off);       off += (size_t)N * D * 4;
    int* row_ptr = (int*)(ws + off);       off += (size_t)(N + 1) * 4;
    int* deg = (int*)(ws + off);           off += (size_t)N * 4;
    int* bsums = (int*)(ws + off);         off += (size_t)((nb + 255) & ~255) * 4;
    int* src_sorted = (int*)(ws + off);    off += (size_t)E * 4;
    float* Wt1 = (float*)(ws + off);       off += (size_t)D * D * 4;
    float* Wt2 = (float*)(ws + off);       off += (size_t)D * D * 4;
    size_t need = off;

    if (ws_size >= need) {
        // ===== CSR path: no float atomics =====
        transpose_kernel<<<(D * D + 255) / 256, 256, 0, stream>>>(W1, Wt1);
        transpose_kernel<<<(D * D + 255) / 256, 256, 0, stream>>>(W2, Wt2);

        hipMemsetAsync(deg, 0, (size_t)N * 4, stream);
        hist_kernel<<<(E + 255) / 256, 256, 0, stream>>>(dst, E, deg);
        scanA_kernel<<<nb, 256, 0, stream>>>(deg, row_ptr, bsums, N);
        scanB_kernel<<<1, 256, 0, stream>>>(bsums, nb);
        scanC_kernel<<<(N + 255) / 256, 256, 0, stream>>>(row_ptr, bsums, N, E);
        hipMemsetAsync(deg, 0, (size_t)N * 4, stream);   // reuse deg as fill
        bucket_kernel<<<(E + 255) / 256, 256, 0, stream>>>(src, dst, E, row_ptr, deg, src_sorted);

        // layer 1: h1 -> d_out, gemm1 in-place (relu) -> x1 in d_out
        aggregate_kernel<<<(N + 7) / 8, 256, 0, stream>>>(
            (const float4*)features, row_ptr, src_sorted, (float4*)out, N);
        gemm_kernel<<<(N + 7) / 8, 256, 0, stream>>>(out, Wt1, b1, out, N, 1);

        // layer 2: h2 -> buf, gemm2 -> d_out
        aggregate_kernel<<<(N + 7) / 8, 256, 0, stream>>>(
            (const float4*)out, row_ptr, src_sorted, (float4*)buf, N);
        gemm_kernel<<<(N + 7) / 8, 256, 0, stream>>>(buf, Wt2, b2, out, N, 0);
    } else {
        // ===== fallback: R0 atomic path =====
        float* agg = (float*)ws;
        float* cnt = (float*)(ws + (size_t)N * D * 4);
        float* fWt1 = (float*)(ws + (size_t)N * D * 4 + (size_t)N * 4);
        float* fWt2 = fWt1 + D * D;

        hipMemsetAsync(agg, 0, (size_t)N * D * 4 + (size_t)N * 4, stream);
        transpose_kernel<<<(D * D + 255) / 256, 256, 0, stream>>>(W1, fWt1);
        transpose_kernel<<<(D * D + 255) / 256, 256, 0, stream>>>(W2, fWt2);
        count_kernel<<<(E + 255) / 256, 256, 0, stream>>>(dst, E, cnt);

        scatter_kernel<<<((size_t)E * 32 + 255) / 256, 256, 0, stream>>>(
            (const float4*)features, src, dst, E, agg);
        finalize_kernel<<<(N * 32 + 255) / 256, 256, 0, stream>>>(
            (const float4*)features, (float4*)agg, cnt, N * 32);
        gemm_kernel<<<(N + 7) / 8, 256, 0, stream>>>(agg, fWt1, b1, out, N, 1);

        hipMemsetAsync(agg, 0, (size_t)N * D * 4, stream);
        scatter_kernel<<<((size_t)E * 32 + 255) / 256, 256, 0, stream>>>(
            (const float4*)out, src, dst, E, agg);
        finalize_kernel<<<(N * 32 + 255) / 256, 256, 0, stream>>>(
            (const float4*)out, (float4*)agg, cnt, N * 32);
        gemm_kernel<<<(N + 7) / 8, 256, 0, stream>>>(agg, fWt2, b2, out, N, 0);
    }
}

// Round 3
// 455.633 us; speedup vs baseline: 13.5737x; 2.3471x over previous
//
#include <hip/hip_runtime.h>

#define D 128

typedef __attribute__((ext_vector_type(8))) short bf16x8;
typedef __attribute__((ext_vector_type(4))) float f32x4;

static __device__ __forceinline__ unsigned short f2bf(float f) {
    unsigned int u = __float_as_uint(f);
    unsigned int r = (u + 0x7fffu + ((u >> 16) & 1u)) >> 16;   // RNE
    return (unsigned short)r;
}
static __device__ __forceinline__ float bf2f(unsigned short u) {
    return __uint_as_float((unsigned int)u << 16);
}

// =================== fp32 -> bf16 bulk convert ===================
__global__ void f2bf_kernel(const float4* __restrict__ in, ushort4* __restrict__ out, int n4) {
    int i = blockIdx.x * blockDim.x + threadIdx.x;
    if (i >= n4) return;
    float4 v = in[i];
    out[i] = make_ushort4(f2bf(v.x), f2bf(v.y), f2bf(v.z), f2bf(v.w));
}

// =================== CSR build ===================
__global__ void hist_kernel(const int* __restrict__ dst, int E, int* __restrict__ deg) {
    int i = blockIdx.x * blockDim.x + threadIdx.x;
    if (i < E) atomicAdd(&deg[dst[i]], 1);
}

__global__ __launch_bounds__(256) void scanA_kernel(const int* __restrict__ deg,
                                                    int* __restrict__ row_ptr,
                                                    int* __restrict__ bsums, int N) {
    __shared__ int sd[256];
    int t = threadIdx.x;
    int base = blockIdx.x * 1024 + t * 4;
    int v[4]; int s = 0;
#pragma unroll
    for (int k = 0; k < 4; ++k) {
        v[k] = (base + k < N) ? deg[base + k] : 0;
        s += v[k];
    }
    sd[t] = s;
    __syncthreads();
    for (int off = 1; off < 256; off <<= 1) {
        int x = (t >= off) ? sd[t - off] : 0;
        __syncthreads();
        sd[t] += x;
        __syncthreads();
    }
    int excl = sd[t] - s;
    if (t == 255) bsums[blockIdx.x] = sd[255];
    int run = excl;
#pragma unroll
    for (int k = 0; k < 4; ++k) {
        if (base + k < N) row_ptr[base + k] = run;
        run += v[k];
    }
}

__global__ __launch_bounds__(256) void scanB_kernel(int* __restrict__ bsums, int nb) {
    __shared__ int sd[256];
    int t = threadIdx.x;
    int carry = 0;
    for (int base = 0; base < nb; base += 256) {
        int i = base + t;
        int v = (i < nb) ? bsums[i] : 0;
        sd[t] = v;
        __syncthreads();
        for (int off = 1; off < 256; off <<= 1) {
            int x = (t >= off) ? sd[t - off] : 0;
            __syncthreads();
            sd[t] += x;
            __syncthreads();
        }
        if (i < nb) bsums[i] = carry + sd[t] - v;
        int tot = sd[255];
        __syncthreads();
        carry += tot;
    }
}

__global__ void scanC_kernel(int* __restrict__ row_ptr, const int* __restrict__ bsums,
                             int N, int E) {
    int i = blockIdx.x * blockDim.x + threadIdx.x;
    if (i < N) row_ptr[i] += bsums[i >> 10];
    if (i == 0) row_ptr[N] = E;
}

__global__ void bucket_kernel(const int* __restrict__ src, const int* __restrict__ dst, int E,
                              const int* __restrict__ row_ptr, int* __restrict__ fill,
                              int* __restrict__ src_sorted) {
    int e = blockIdx.x * blockDim.x + threadIdx.x;
    if (e < E) {
        int t = dst[e];
        int p = atomicAdd(&fill[t], 1);
        src_sorted[row_ptr[t] + p] = src[e];
    }
}

// =================== aggregation (bf16 in/out, fp32 accumulate) ===================
// 32 lanes per node, ushort4 (4 bf16) per lane: out = x[node] + sum(x[src])/max(deg,1)
__global__ __launch_bounds__(256) void aggregate_bf16(const ushort4* __restrict__ x,
                                                      const int* __restrict__ row_ptr,
                                                      const int* __restrict__ src_sorted,
                                                      ushort4* __restrict__ out, int N) {
    int node = blockIdx.x * 8 + (threadIdx.x >> 5);
    if (node >= N) return;
    int c = threadIdx.x & 31;
    int beg = row_ptr[node], end = row_ptr[node + 1];
    float ax = 0.f, ay = 0.f, az = 0.f, aw = 0.f;
    int j = beg;
    for (; j + 4 <= end; j += 4) {
        int s0 = src_sorted[j + 0];
        int s1 = src_sorted[j + 1];
        int s2 = src_sorted[j + 2];
        int s3 = src_sorted[j + 3];
        ushort4 v0 = x[(size_t)s0 * 32 + c];
        ushort4 v1 = x[(size_t)s1 * 32 + c];
        ushort4 v2 = x[(size_t)s2 * 32 + c];
        ushort4 v3 = x[(size_t)s3 * 32 + c];
        ax += bf2f(v0.x) + bf2f(v1.x) + bf2f(v2.x) + bf2f(v3.x);
        ay += bf2f(v0.y) + bf2f(v1.y) + bf2f(v2.y) + bf2f(v3.y);
        az += bf2f(v0.z) + bf2f(v1.z) + bf2f(v2.z) + bf2f(v3.z);
        aw += bf2f(v0.w) + bf2f(v1.w) + bf2f(v2.w) + bf2f(v3.w);
    }
    for (; j < end; ++j) {
        int s = src_sorted[j];
        ushort4 v = x[(size_t)s * 32 + c];
        ax += bf2f(v.x); ay += bf2f(v.y); az += bf2f(v.z); aw += bf2f(v.w);
    }
    float inv = 1.0f / fmaxf((float)(end - beg), 1.0f);
    ushort4 xv = x[(size_t)node * 32 + c];
    out[(size_t)node * 32 + c] = make_ushort4(
        f2bf(bf2f(xv.x) + ax * inv),
        f2bf(bf2f(xv.y) + ay * inv),
        f2bf(bf2f(xv.z) + az * inv),
        f2bf(bf2f(xv.w) + aw * inv));
}

// =================== MFMA GEMM ===================
// out[row][col] = act( A[row] . W[col] + bias[col] ), A bf16 [N][128], W fp32 [128][128]
// Block: 128 rows x 128 cols, 4 waves, each wave 32 rows (2 row-tiles x 8 col-tiles).
// W staged in LDS as bf16 in native [col][k] layout (= MFMA B-operand layout),
// row stride 136 bf16 -> 2-way bank aliasing only (free).
__global__ __launch_bounds__(256) void gemm_mfma(const unsigned short* __restrict__ A,
                                                 const float* __restrict__ W,
                                                 const float* __restrict__ bias,
                                                 unsigned short* __restrict__ outb,
                                                 float* __restrict__ outf,
                                                 int N, int relu) {
    __shared__ __align__(16) short Wl[128 * 136];
    int t = threadIdx.x;
    {   // convert W fp32 -> bf16 into LDS: 2 threads per row, 64 elems each
        int row = t >> 1, half = t & 1;
        const float* wsrc = W + row * D + half * 64;
        short* wdst = Wl + row * 136 + half * 64;
#pragma unroll
        for (int i = 0; i < 16; ++i) {
            float4 v = *(const float4*)(wsrc + i * 4);
            *(ushort4*)(wdst + i * 4) =
                make_ushort4(f2bf(v.x), f2bf(v.y), f2bf(v.z), f2bf(v.w));
        }
    }
    __syncthreads();

    int wave = t >> 6;
    int lane = t & 63;
    int quad = lane >> 4;
    int l16  = lane & 15;
    int row0 = blockIdx.x * 128 + wave * 32;

    f32x4 acc[2][8];
#pragma unroll
    for (int rt = 0; rt < 2; ++rt)
#pragma unroll
        for (int ct = 0; ct < 8; ++ct)
            acc[rt][ct] = (f32x4){0.f, 0.f, 0.f, 0.f};

    const unsigned short* a0 = A + (size_t)(row0 + l16) * D + quad * 8;
    const unsigned short* a1 = a0 + (size_t)16 * D;
    bool ok0 = (row0 + l16) < N;
    bool ok1 = (row0 + 16 + l16) < N;
    bf16x8 zz = {0, 0, 0, 0, 0, 0, 0, 0};

#pragma unroll
    for (int ks = 0; ks < 4; ++ks) {
        bf16x8 af0 = ok0 ? *(const bf16x8*)(a0 + ks * 32) : zz;
        bf16x8 af1 = ok1 ? *(const bf16x8*)(a1 + ks * 32) : zz;
#pragma unroll
        for (int ct = 0; ct < 8; ++ct) {
            bf16x8 bfr = *(const bf16x8*)(Wl + (ct * 16 + l16) * 136 + ks * 32 + quad * 8);
            acc[0][ct] = __builtin_amdgcn_mfma_f32_16x16x32_bf16(af0, bfr, acc[0][ct], 0, 0, 0);
            acc[1][ct] = __builtin_amdgcn_mfma_f32_16x16x32_bf16(af1, bfr, acc[1][ct], 0, 0, 0);
        }
    }

    // epilogue: C/D layout col=lane&15, row=quad*4+reg
#pragma unroll
    for (int rt = 0; rt < 2; ++rt) {
        int rbase = row0 + rt * 16 + quad * 4;
#pragma unroll
        for (int ct = 0; ct < 8; ++ct) {
            int col = ct * 16 + l16;
            float bb = bias[col];
#pragma unroll
            for (int r = 0; r < 4; ++r) {
                int row = rbase + r;
                if (row < N) {
                    float v = acc[rt][ct][r] + bb;
                    if (relu) v = fmaxf(v, 0.f);
                    if (outb) outb[(size_t)row * D + col] = f2bf(v);
                    else      outf[(size_t)row * D + col] = v;
                }
            }
        }
    }
}

extern "C" void kernel_launch(void* const* d_in, const int* in_sizes, int n_in,
                              void* d_out, int out_size, void* d_ws, size_t ws_size,
                              hipStream_t stream) {
    const float* features = (const float*)d_in[0];
    const int*   src      = (const int*)d_in[1];
    const int*   dst      = (const int*)d_in[2];
    const float* W1       = (const float*)d_in[3];
    const float* b1       = (const float*)d_in[4];
    const float* W2       = (const float*)d_in[5];
    const float* b2       = (const float*)d_in[6];
    float* out = (float*)d_out;

    int N = in_sizes[0] / D;     // 100000
    int E = in_sizes[1];         // 1600000
    int nb = (N + 1023) / 1024;

    // ws layout: bufA [N*D bf16] | bufB [N*D bf16] | row_ptr [(N+1)] | deg [N]
    //            | bsums [pad] | src_sorted [E]
    char* ws = (char*)d_ws;
    size_t off = 0;
    unsigned short* bufA = (unsigned short*)(ws + off); off += (size_t)N * D * 2;
    unsigned short* bufB = (unsigned short*)(ws + off); off += (size_t)N * D * 2;
    int* row_ptr = (int*)(ws + off);    off += (size_t)(N + 1) * 4;
    int* deg = (int*)(ws + off);        off += (size_t)N * 4;
    int* bsums = (int*)(ws + off);      off += (size_t)((nb + 255) & ~255) * 4;
    int* src_sorted = (int*)(ws + off); off += (size_t)E * 4;

    // features -> bf16 (bufA)
    f2bf_kernel<<<(N * 32 + 255) / 256, 256, 0, stream>>>(
        (const float4*)features, (ushort4*)bufA, N * 32);

    // CSR build
    hipMemsetAsync(deg, 0, (size_t)N * 4, stream);
    hist_kernel<<<(E + 255) / 256, 256, 0, stream>>>(dst, E, deg);
    scanA_kernel<<<nb, 256, 0, stream>>>(deg, row_ptr, bsums, N);
    scanB_kernel<<<1, 256, 0, stream>>>(bsums, nb);
    scanC_kernel<<<(N + 255) / 256, 256, 0, stream>>>(row_ptr, bsums, N, E);
    hipMemsetAsync(deg, 0, (size_t)N * 4, stream);   // reuse as fill
    bucket_kernel<<<(E + 255) / 256, 256, 0, stream>>>(src, dst, E, row_ptr, deg, src_sorted);

    int gemm_grid = (N + 127) / 128;

    // layer 1: h1 = agg(xb) -> bufB;  x1 = relu(h1.W1^T + b1) -> bufA (bf16)
    aggregate_bf16<<<(N + 7) / 8, 256, 0, stream>>>(
        (const ushort4*)bufA, row_ptr, src_sorted, (ushort4*)bufB, N);
    gemm_mfma<<<gemm_grid, 256, 0, stream>>>(bufB, W1, b1, bufA, (float*)nullptr, N, 1);

    // layer 2: h2 = agg(x1) -> bufB;  out = h2.W2^T + b2 -> d_out (fp32)
    aggregate_bf16<<<(N + 7) / 8, 256, 0, stream>>>(
        (const ushort4*)bufA, row_ptr, src_sorted, (ushort4*)bufB, N);
    gemm_mfma<<<gemm_grid, 256, 0, stream>>>(bufB, W2, b2, (unsigned short*)nullptr, out, N, 0);
}